// Round 3
// baseline (242.689 us; speedup 1.0000x reference)
//
#include <hip/hip_runtime.h>
#include <stdint.h>

typedef unsigned short u16;
typedef __attribute__((ext_vector_type(8))) __bf16 bf16x8;
typedef __attribute__((ext_vector_type(4))) float f32x4;

__device__ __forceinline__ float bf2f(u16 u){
  unsigned int x = ((unsigned int)u) << 16;
  return __builtin_bit_cast(float, x);
}
__device__ __forceinline__ u16 f2bf(float f){
  unsigned int u = __builtin_bit_cast(unsigned int, f);
  u += 0x7fffu + ((u >> 16) & 1u);   // RNE
  return (u16)(u >> 16);
}

// ------- transpose+convert: out_bf16[C][R] = in_f32[R][C], 64x64 tiles -------
__global__ __launch_bounds__(256) void transpose64(const float* __restrict__ in,
                                                   u16* __restrict__ out,
                                                   int R, int C){
  __shared__ u16 t[64][65];
  const int c0 = blockIdx.x * 64, r0 = blockIdx.y * 64;
  const int tid = threadIdx.x;
  const int rr = tid >> 3;          // 0..31
  const int cc = (tid & 7) * 8;     // 0..56
#pragma unroll
  for (int i = 0; i < 2; i++){
    int r = i * 32 + rr;
    const float* p = in + (size_t)(r0 + r) * C + c0 + cc;
    f32x4 v0 = *(const f32x4*)p;
    f32x4 v1 = *(const f32x4*)(p + 4);
#pragma unroll
    for (int j = 0; j < 4; j++){ t[r][cc + j] = f2bf(v0[j]); t[r][cc + 4 + j] = f2bf(v1[j]); }
  }
  __syncthreads();
#pragma unroll
  for (int i = 0; i < 2; i++){
    int c = i * 32 + rr;
    u16 tmp[8];
#pragma unroll
    for (int j = 0; j < 8; j++) tmp[j] = t[cc + j][c];
    *(bf16x8*)(out + (size_t)(c0 + c) * R + r0 + cc) = *(const bf16x8*)tmp;
  }
}

// ---------------- GEMM: C[M][N] = A[M][K] * Bt[N][K]^T + bias ----------------
// 128x128 tile, 4 waves (2x2 of 64x64), BK=32, reg-staged LDS.
// XOR swizzle: LDS(row, chunk) holds global chunk (chunk ^ ((row>>1)&3)).
// AF32: A is fp32 (converted to bf16 while staging). OUTF32: C is fp32.
template<bool AF32, bool OUTF32>
__global__ __launch_bounds__(256, 2) void gemm_bt(const void* __restrict__ Av,
                                                  const u16* __restrict__ Bt,
                                                  const float* __restrict__ bias,
                                                  void* __restrict__ Cv,
                                                  int M, int N, int K){
  __shared__ u16 As[128 * 32];
  __shared__ u16 Bs[128 * 32];
  const int bn = blockIdx.x, bm = blockIdx.y;
  const int tid = threadIdx.x, w = tid >> 6, l = tid & 63;
  const int lo = l & 15, hi = l >> 4;
  const int wr = (w >> 1) * 64, wc = (w & 1) * 64;
  f32x4 acc[4][4] = {};

  for (int k0 = 0; k0 < K; k0 += 32){
#pragma unroll
    for (int i = 0; i < 2; i++){
      int cid = i * 256 + tid;          // 512 chunks of 8 elems per tile
      int row = cid >> 2, cd = cid & 3;
      int cs = cd ^ ((row >> 1) & 3);   // source chunk (swizzle involution)
      if (AF32){
        const float* ap = (const float*)Av + (size_t)(bm * 128 + row) * K + k0 + cs * 8;
        f32x4 a0 = *(const f32x4*)ap;
        f32x4 a1 = *(const f32x4*)(ap + 4);
        u16 tmp[8];
#pragma unroll
        for (int j = 0; j < 4; j++){ tmp[j] = f2bf(a0[j]); tmp[4 + j] = f2bf(a1[j]); }
        *(bf16x8*)((char*)As + row * 64 + cd * 16) = *(const bf16x8*)tmp;
      } else {
        bf16x8 av = *(const bf16x8*)((const u16*)Av + (size_t)(bm * 128 + row) * K + k0 + cs * 8);
        *(bf16x8*)((char*)As + row * 64 + cd * 16) = av;
      }
      bf16x8 bv = *(const bf16x8*)(Bt + (size_t)(bn * 128 + row) * K + k0 + cs * 8);
      *(bf16x8*)((char*)Bs + row * 64 + cd * 16) = bv;
    }
    __syncthreads();
    bf16x8 a[4], b[4];
#pragma unroll
    for (int mi = 0; mi < 4; mi++){
      int row = wr + mi * 16 + lo;
      unsigned byte = (unsigned)(row * 64 + hi * 16) ^ (((row >> 1) & 3) << 4);
      a[mi] = *(const bf16x8*)((const char*)As + byte);
    }
#pragma unroll
    for (int ni = 0; ni < 4; ni++){
      int row = wc + ni * 16 + lo;
      unsigned byte = (unsigned)(row * 64 + hi * 16) ^ (((row >> 1) & 3) << 4);
      b[ni] = *(const bf16x8*)((const char*)Bs + byte);
    }
#pragma unroll
    for (int mi = 0; mi < 4; mi++)
#pragma unroll
      for (int ni = 0; ni < 4; ni++)
        acc[mi][ni] = __builtin_amdgcn_mfma_f32_16x16x32_bf16(a[mi], b[ni], acc[mi][ni], 0, 0, 0);
    __syncthreads();
  }
  // epilogue: C/D map col=lane&15, row=(lane>>4)*4+reg  [m89-verified]
#pragma unroll
  for (int mi = 0; mi < 4; mi++){
#pragma unroll
    for (int r = 0; r < 4; r++){
      int grow = bm * 128 + wr + mi * 16 + hi * 4 + r;
#pragma unroll
      for (int ni = 0; ni < 4; ni++){
        int col = ni * 16 + lo;
        float v = acc[mi][ni][r] + bias[bn * 128 + wc + col];
        if (OUTF32)
          ((float*)Cv)[(size_t)grow * N + bn * 128 + wc + col] = v;
        else
          ((u16*)Cv)[(size_t)grow * N + bn * 128 + wc + col] = f2bf(v);
      }
    }
  }
}

// ---------------- RoPE in-place on q,k thirds of qkv[4096][3072] -------------
__global__ __launch_bounds__(256) void rope_inplace(u16* __restrict__ qkv,
                                                    const float* __restrict__ cosb,
                                                    const float* __restrict__ sinb){
  int tid = blockIdx.x * 256 + threadIdx.x;  // 4096*16*32 threads
  int i = tid & 31;
  int h = (tid >> 5) & 15;
  int m = tid >> 9;
  int s = m & 2047;
  u16* row = qkv + (size_t)m * 3072;
  float c  = cosb[s * 32 + i];
  float sn = sinb[s * 32 + i];
  int qi = h * 64 + 2 * i;
  float e = bf2f(row[qi]), o = bf2f(row[qi + 1]);
  row[qi]     = f2bf(e * c - o * sn);
  row[qi + 1] = f2bf(e * sn + o * c);
  int ki = 1024 + qi;
  e = bf2f(row[ki]); o = bf2f(row[ki + 1]);
  row[ki]     = f2bf(e * c - o * sn);
  row[ki + 1] = f2bf(e * sn + o * c);
}

// ---------------- flash attention, causal, online softmax --------------------
// grid (32 qtiles, 32 b*h); 4 waves/block, each wave owns 16 q-rows.
// K tile [64][64] reg-staged, XOR-swizzled: LDS(row,chunk)=global(chunk^(row&7));
// V tile stored transposed [d][s] (swizzled); P round-trips per-wave LDS.
__global__ __launch_bounds__(256, 2) void flash_attn(const u16* __restrict__ qkv,
                                                     u16* __restrict__ Oout){
  const int S = 2048, LD = 3072;
  const int qt = blockIdx.x, bh = blockIdx.y;
  const int b = bh >> 4, h = bh & 15;
  const u16* base = qkv + (size_t)b * S * LD;
  const u16* Qp = base + h * 64;
  const u16* Kp = base + 1024 + h * 64;
  const u16* Vp = base + 2048 + h * 64;
  const int tid = threadIdx.x, w = tid >> 6, l = tid & 63;
  const int lo = l & 15, hi = l >> 4;
  __shared__ u16 Ks[64 * 64];
  __shared__ u16 Vs[64 * 64];      // transposed [d][s], swizzled
  __shared__ u16 Ps[4][16 * 64];   // per-wave P, swizzled
  const int qbase = qt * 64;

  bf16x8 qf[2];
#pragma unroll
  for (int c = 0; c < 2; c++)
    qf[c] = *(const bf16x8*)(Qp + (size_t)(qbase + w * 16 + lo) * LD + c * 32 + hi * 8);

  f32x4 o[4] = {};
  float m_r[4], l_r[4];
#pragma unroll
  for (int r = 0; r < 4; r++){ m_r[r] = -1e30f; l_r[r] = 0.f; }

  for (int kt = 0; kt <= qt; kt++){
    // ---- stage K (reg-staged, swizzled) ----
#pragma unroll
    for (int i = 0; i < 2; i++){
      int cid = i * 256 + tid;          // 512 chunks: 64 rows x 8 chunks
      int row = cid >> 3, cd = cid & 7;
      int cs = cd ^ (row & 7);
      bf16x8 kv = *(const bf16x8*)(Kp + (size_t)(kt * 64 + row) * LD + cs * 8);
      *(bf16x8*)((char*)Ks + row * 128 + cd * 16) = kv;
    }
    // ---- stage V transposed + swizzled ----
#pragma unroll
    for (int i = 0; i < 2; i++){
      int s  = i * 32 + (tid >> 3);
      int d0 = (tid & 7) * 8;
      bf16x8 vv = *(const bf16x8*)(Vp + (size_t)(kt * 64 + s) * LD + d0);
#pragma unroll
      for (int j = 0; j < 8; j++){
        int d = d0 + j;
        unsigned byte = ((unsigned)(d * 128 + s * 2)) ^ ((d & 7) << 4);
        *(u16*)((char*)Vs + byte) = __builtin_bit_cast(u16, (__bf16)vv[j]);
      }
    }
    __syncthreads();
    // ---- S = Q K^T ----
    f32x4 sa[4] = {};
#pragma unroll
    for (int c = 0; c < 2; c++)
#pragma unroll
      for (int f = 0; f < 4; f++){
        int srow = f * 16 + lo;
        unsigned byte = ((unsigned)(srow * 128 + c * 64 + hi * 16)) ^ ((srow & 7) << 4);
        bf16x8 kb = *(const bf16x8*)((const char*)Ks + byte);
        sa[f] = __builtin_amdgcn_mfma_f32_16x16x32_bf16(qf[c], kb, sa[f], 0, 0, 0);
      }
    // ---- scale + causal mask ----
    int sq0 = qbase + w * 16 + hi * 4;
#pragma unroll
    for (int f = 0; f < 4; f++){
      int sk = kt * 64 + f * 16 + lo;
#pragma unroll
      for (int r = 0; r < 4; r++){
        float v = sa[f][r] * 0.125f;
        sa[f][r] = (sk <= sq0 + r) ? v : -1e30f;
      }
    }
    // ---- online softmax (row reduce across the 16-lane lo group) ----
    float pb[4][4];
#pragma unroll
    for (int r = 0; r < 4; r++){
      float mv = fmaxf(fmaxf(sa[0][r], sa[1][r]), fmaxf(sa[2][r], sa[3][r]));
#pragma unroll
      for (int d = 1; d < 16; d <<= 1) mv = fmaxf(mv, __shfl_xor(mv, d, 64));
      float mnew = fmaxf(m_r[r], mv);
      float corr = __expf(m_r[r] - mnew);
      m_r[r] = mnew;
      l_r[r] *= corr;
      o[0][r] *= corr; o[1][r] *= corr; o[2][r] *= corr; o[3][r] *= corr;
      float s0 = 0.f;
#pragma unroll
      for (int f = 0; f < 4; f++){
        float p = __expf(sa[f][r] - mnew);
        pb[f][r] = p;
        s0 += p;
      }
#pragma unroll
      for (int d = 1; d < 16; d <<= 1) s0 += __shfl_xor(s0, d, 64);
      l_r[r] += s0;
    }
    // ---- P -> per-wave LDS (bf16, swizzled) ----
#pragma unroll
    for (int f = 0; f < 4; f++)
#pragma unroll
      for (int r = 0; r < 4; r++){
        int prow = hi * 4 + r, pcol = f * 16 + lo;
        unsigned byte = ((unsigned)(prow * 128 + pcol * 2)) ^ ((prow & 7) << 4);
        *(u16*)((char*)&Ps[w][0] + byte) = f2bf(pb[f][r]);
      }
    // ---- O += P V ----
    bf16x8 pa[2];
#pragma unroll
    for (int c = 0; c < 2; c++){
      unsigned byte = ((unsigned)(lo * 128 + c * 64 + hi * 16)) ^ ((lo & 7) << 4);
      pa[c] = *(const bf16x8*)((const char*)&Ps[w][0] + byte);
    }
#pragma unroll
    for (int fd = 0; fd < 4; fd++)
#pragma unroll
      for (int c = 0; c < 2; c++){
        int drow = fd * 16 + lo;
        unsigned byte = ((unsigned)(drow * 128 + c * 64 + hi * 16)) ^ ((drow & 7) << 4);
        bf16x8 vb = *(const bf16x8*)((const char*)Vs + byte);
        o[fd] = __builtin_amdgcn_mfma_f32_16x16x32_bf16(pa[c], vb, o[fd], 0, 0, 0);
      }
    __syncthreads();
  }
  // ---- normalize + store [b][s][h*64+d] ----
#pragma unroll
  for (int r = 0; r < 4; r++){
    float inv = 1.0f / l_r[r];
    int srow = qbase + w * 16 + hi * 4 + r;
    u16* orow = Oout + (size_t)(b * S + srow) * 1024 + h * 64;
#pragma unroll
    for (int fd = 0; fd < 4; fd++)
      orow[fd * 16 + lo] = f2bf(o[fd][r] * inv);
  }
}

extern "C" void kernel_launch(void* const* d_in, const int* in_sizes, int n_in,
                              void* d_out, int out_size, void* d_ws, size_t ws_size,
                              hipStream_t stream){
  const float* x     = (const float*)d_in[0];
  const float* w_qkv = (const float*)d_in[1];
  const float* b_qkv = (const float*)d_in[2];
  const float* w_out = (const float*)d_in[3];
  const float* b_out = (const float*)d_in[4];
  const float* cosb  = (const float*)d_in[5];
  const float* sinb  = (const float*)d_in[6];
  // d_in[7] = mask: causal, implemented analytically.
  float* out = (float*)d_out;
  char* ws = (char*)d_ws;
  u16* wT1  = (u16*)(ws);              // w_qkv^T bf16 [3072][1024]  (6.3 MB)
  u16* wT2  = (u16*)(ws + 6291456);    // w_out^T bf16 [1024][1024]  (2.1 MB)
  u16* qkv  = (u16*)(ws + 8388608);    // bf16 [4096][3072]          (25.2 MB)
  u16* attn = (u16*)(ws + 33554432);   // bf16 [4096][1024]          (8.4 MB)

  transpose64<<<dim3(48, 16), 256, 0, stream>>>(w_qkv, wT1, 1024, 3072);
  transpose64<<<dim3(16, 16), 256, 0, stream>>>(w_out, wT2, 1024, 1024);
  gemm_bt<true , false><<<dim3(24, 32), 256, 0, stream>>>(x,    wT1, b_qkv, qkv, 4096, 3072, 1024);
  rope_inplace<<<8192, 256, 0, stream>>>(qkv, cosb, sinb);
  flash_attn<<<dim3(32, 32), 256, 0, stream>>>(qkv, attn);
  gemm_bt<false, true ><<<dim3(8, 32), 256, 0, stream>>>(attn, wT2, b_out, out, 4096, 1024, 1024);
}